// Round 5
// baseline (156.560 us; speedup 1.0000x reference)
//
#include <hip/hip_runtime.h>

#define IMW 512
#define NP 4096
#define NB 8

#define GATHER_BLOCKS 32               // 32 blocks x 1024 thr = 1 thread per point
#define DIST_BLOCKS 8                  // 1 block per batch, binned neighbor search
#define TOTAL_BLOCKS (GATHER_BLOCKS + DIST_BLOCKS)

#define NCELL 20                       // 20x20 grid of 0.05-sized cells
#define NCELL2 400

// Gaussian kernel, sigma = 0.3*((11-1)*0.5 - 1) + 0.8 = 2.0, normalized (f64-accurate, rounded to f32)
__device__ constexpr float KW[11] = {
    0.00881223f, 0.02714359f, 0.06511407f, 0.12164908f, 0.17699836f,
    0.20056542f, 0.17699836f, 0.12164908f, 0.06511407f, 0.02714359f, 0.00881223f};

// reflect map: valid for r in [-5, 517]; matches both the blur pad and the intensity pad
__device__ __forceinline__ int refl(int r) {
    r = r < 0 ? -r : r;
    return r > 511 ? 1022 - r : r;
}

// blocks [0,32): intensity gather w/ inline 2D blur, row-major taps (1 pt/thread)
// blocks [32,40): dist-push via 20x20 spatial binning (counting sort in LDS, 3x3 neighbor ranges)
__global__ __launch_bounds__(1024)
void fused_compute(const float* __restrict__ trace, const float* __restrict__ img,
                   float* __restrict__ partials) {
    const int tid = threadIdx.x;
    const int bx = blockIdx.x;
    __shared__ float2 sorted[NP];      // 32 KB
    __shared__ int cellcnt[NCELL2];
    __shared__ int cellstart[NCELL2];
    __shared__ int cursor[NCELL2];
    __shared__ int offs[512];
    __shared__ float red[16];
    float local;

    if (bx < GATHER_BLOCKS) {
        // ---- intensity gather: one point per thread ----
        const int p = bx * 1024 + tid;             // [0, 32768)
        const int b = p >> 12;
        const float2 t2 = ((const float2*)trace)[b * NP + (p & (NP - 1))];
        const float idx0 = t2.x * 512.f, idx1 = t2.y * 512.f;
        const float i0f = floorf(idx0 + 0.5f), j0f = floorf(idx1 + 0.5f);
        const float wi = idx0 - i0f, wj = idx1 - j0f;
        const int i0 = (int)i0f, j0 = (int)j0f;
        const int mi0 = refl(i0), mi1 = refl(i0 + 1);
        const int mj0 = refl(j0), mj1 = refl(j0 + 1);
        const int ilo = min(mi0, mi1), jlo = min(mj0, mj1);
        const bool sr = mi0 > mi1, sc = mj0 > mj1;   // |mi0-mi1| == |mj0-mj1| == 1 always
        const float* srcb = img + b * (IMW * IMW);

        int cc[12], R[12];
#pragma unroll
        for (int c = 0; c < 12; ++c) cc[c] = refl(jlo - 5 + c);
#pragma unroll
        for (int r = 0; r < 12; ++r) R[r] = refl(ilo - 5 + r) * IMW;

        // row-major: horizontal blur per row (cache-line friendly), vertical accumulate on the fly
        float A_lo = 0.f, A_hi = 0.f, B_lo = 0.f, B_hi = 0.f;
#pragma unroll
        for (int r = 0; r < 12; ++r) {
            const float* base = srcb + R[r];
            float lo = 0.f, hi = 0.f;
#pragma unroll
            for (int c = 0; c < 12; ++c) {
                const float v = base[cc[c]];
                if (c < 11) lo = fmaf(KW[c], v, lo);       // H(row_r, jlo)
                if (c > 0) hi = fmaf(KW[c - 1], v, hi);    // H(row_r, jlo+1)
            }
            if (r < 11) { A_lo = fmaf(KW[r], lo, A_lo); B_lo = fmaf(KW[r], hi, B_lo); }
            if (r > 0)  { A_hi = fmaf(KW[r - 1], lo, A_hi); B_hi = fmaf(KW[r - 1], hi, B_hi); }
        }
        const float yA  = sr ? A_hi : A_lo;   // blurred (mi0, jlo)
        const float yA1 = sr ? A_lo : A_hi;   // blurred (mi1, jlo)
        const float yB  = sr ? B_hi : B_lo;   // blurred (mi0, jlo+1)
        const float yB1 = sr ? B_lo : B_hi;   // blurred (mi1, jlo+1)
        const float y00 = sc ? yB : yA;
        const float y01 = sc ? yA : yB;
        const float y10 = sc ? yB1 : yA1;
        local = 0.5f * ((1.f - wi) * y00 + wi * y10 + (1.f - wj) * y00 + wj * y01);
    } else {
        // ---- dist push, spatially binned: only d < 0.05 pairs contribute ----
        const int b = bx - GATHER_BLOCKS;
        const float2* tb = (const float2*)(trace + b * NP * 2);
        float2 r4[4];
        int c4[4];
#pragma unroll
        for (int k = 0; k < 4; ++k) {
            const float2 pt = tb[tid + 1024 * k];
            r4[k] = pt;
            const int cx = min((int)(pt.x * 20.f), NCELL - 1);
            const int cy = min((int)(pt.y * 20.f), NCELL - 1);
            c4[k] = cy * NCELL + cx;
        }
        if (tid < NCELL2) cellcnt[tid] = 0;
        __syncthreads();
#pragma unroll
        for (int k = 0; k < 4; ++k) atomicAdd(&cellcnt[c4[k]], 1);
        __syncthreads();
        // Hillis-Steele inclusive scan over 400 (padded to 512) cell counts
        if (tid < 512) offs[tid] = (tid < NCELL2) ? cellcnt[tid] : 0;
        __syncthreads();
        for (int s = 1; s < 512; s <<= 1) {
            int v = 0;
            if (tid < 512 && tid >= s) v = offs[tid - s];
            __syncthreads();
            if (tid < 512) offs[tid] += v;
            __syncthreads();
        }
        if (tid < NCELL2) {
            const int st = offs[tid] - cellcnt[tid];
            cellstart[tid] = st;
            cursor[tid] = st;
        }
        __syncthreads();
#pragma unroll
        for (int k = 0; k < 4; ++k) {
            const int pos = atomicAdd(&cursor[c4[k]], 1);
            sorted[pos] = r4[k];
        }
        __syncthreads();
        // neighbor search: 3 contiguous cell-ranges per point (cells row-contiguous)
        float s = 0.f;
#pragma unroll
        for (int k = 0; k < 4; ++k) {
            const float2 p = r4[k];
            const int cy = c4[k] / NCELL, cx = c4[k] - cy * NCELL;
            const int x0 = max(cx - 1, 0), x1 = min(cx + 1, NCELL - 1);
            const int y0 = max(cy - 1, 0), y1 = min(cy + 1, NCELL - 1);
            for (int ny = y0; ny <= y1; ++ny) {
                const int rb = ny * NCELL;
                int q = cellstart[rb + x0];
                const int qe = cellstart[rb + x1] + cellcnt[rb + x1];
                for (; q < qe; ++q) {
                    const float2 o = sorted[q];
                    const float dx = p.x - o.x, dy = p.y - o.y;
                    const float d2 = fmaf(dx, dx, dy * dy);
                    // self-pair gives exactly 0.05 (sqrt(0)=0); subtracted analytically in finalize
                    s += (d2 < 0.0025f) ? (0.05f - __builtin_amdgcn_sqrtf(d2)) : 0.f;
                }
            }
        }
        local = s;
    }

    // ---- block reduction, plain store of this block's partial ----
    for (int o = 32; o; o >>= 1) local += __shfl_down(local, o, 64);
    if ((tid & 63) == 0) red[tid >> 6] = local;
    __syncthreads();
    if (tid == 0) {
        float t = 0.f;
#pragma unroll
        for (int w = 0; w < 16; ++w) t += red[w];
        partials[bx] = t;
    }
}

// Finalize: slots [0,32)=gather intensity sums, [32,40)=dist contribution sums (ordered + self)
__global__ __launch_bounds__(64)
void finalize(const float* __restrict__ partials, float* __restrict__ out) {
    const int tid = threadIdx.x;
    float sg = 0.f, sd = 0.f;
    if (tid < TOTAL_BLOCKS) {
        const float v = partials[tid];
        if (tid < GATHER_BLOCKS) sg = v; else sd = v;
    }
    for (int o = 32; o; o >>= 1) {
        sg += __shfl_down(sg, o, 64);
        sd += __shfl_down(sd, o, 64);
    }
    if (tid == 0) {
        const double Sd = (double)sd;   // sum of max(0.05-d,0), ordered pairs + 32768 self-pairs
        const double S1 = (double)sg;   // sum of intensities
        // upper-pair sum = (Sd - 32768*0.05)/2 ; dp = that / (8 * 4096*4095/2)
        const double dp = (Sd - 1638.4) / 134184960.0;
        const double il = 255.0 - S1 / 32768.0;
        out[0] = (float)(dp + il);
    }
}

extern "C" void kernel_launch(void* const* d_in, const int* in_sizes, int n_in,
                              void* d_out, int out_size, void* d_ws, size_t ws_size,
                              hipStream_t stream) {
    const float* trace = (const float*)d_in[0];
    const float* img = (const float*)d_in[1];
    float* partials = (float*)d_ws;
    float* out = (float*)d_out;

    fused_compute<<<TOTAL_BLOCKS, 1024, 0, stream>>>(trace, img, partials);
    finalize<<<1, 64, 0, stream>>>(partials, out);
}